// Round 1
// baseline (1104.798 us; speedup 1.0000x reference)
//
#include <hip/hip_runtime.h>
#include <hip/hip_bf16.h>
#include <cstdint>
#include <cstddef>

#define B_ 4
#define N_ 2048
#define M_ 2048
#define C_ 512
#define H_ 8
#define DH_ 64

typedef __bf16 bf16;
typedef bf16 bf16x8 __attribute__((ext_vector_type(8)));
typedef float f32x4 __attribute__((ext_vector_type(4)));

static __device__ __forceinline__ bf16 f2bf(float f) { return (bf16)f; }

// ---------------- transpose W (f32 -> bf16): Wt[c][k] = W[k][c] -------------
__global__ __launch_bounds__(1024) void transpose_w(const float* __restrict__ W,
                                                    bf16* __restrict__ Wt) {
  __shared__ float t[32][33];
  int c0 = blockIdx.x * 32, k0 = blockIdx.y * 32;
  int tx = threadIdx.x, ty = threadIdx.y;
  t[ty][tx] = W[(k0 + ty) * C_ + c0 + tx];
  __syncthreads();
  Wt[(c0 + ty) * C_ + k0 + tx] = f2bf(t[tx][ty]);
}

// ---------------- transpose V (bf16): Vt[b][c][m] = Vp[b][m][c] -------------
__global__ __launch_bounds__(1024) void transpose_v(const bf16* __restrict__ Vp,
                                                    bf16* __restrict__ Vt) {
  __shared__ bf16 t[32][33];
  int b = blockIdx.z;
  int m0 = blockIdx.x * 32, c0 = blockIdx.y * 32;
  int tx = threadIdx.x, ty = threadIdx.y;
  t[ty][tx] = Vp[((size_t)b * M_ + m0 + ty) * C_ + c0 + tx];
  __syncthreads();
  Vt[((size_t)b * C_ + c0 + ty) * M_ + m0 + tx] = t[tx][ty];
}

// ---------------- projection GEMM: Out[r][c] = X[r][:] @ W[:][c] + bias[c] --
// X: (8192, 512) f32 ; Wt: (512c, 512k) bf16 ; Out: (8192, 512) bf16
__global__ __launch_bounds__(256) void proj_gemm(const float* __restrict__ X,
                                                 const bf16* __restrict__ Wt,
                                                 const float* __restrict__ bias,
                                                 bf16* __restrict__ Out) {
  __shared__ bf16 As[64][40];  // rows r, k
  __shared__ bf16 Bs[64][40];  // rows c, k
  int r0 = blockIdx.y * 64;
  int c0 = blockIdx.x * 64;
  int t = threadIdx.x;
  int w = t >> 6, lane = t & 63, g = lane >> 4, li = lane & 15;
  int wr = (w >> 1) * 32, wc = (w & 1) * 32;
  int arow = t >> 2, acol = (t & 3) * 8;

  f32x4 acc[2][2];
#pragma unroll
  for (int i = 0; i < 2; ++i)
#pragma unroll
    for (int j = 0; j < 2; ++j)
#pragma unroll
      for (int q = 0; q < 4; ++q) acc[i][j][q] = 0.0f;

  for (int k0 = 0; k0 < C_; k0 += 32) {
    __syncthreads();
    {
      const float* src = X + (size_t)(r0 + arow) * C_ + k0 + acol;
      float4 x0 = *(const float4*)src;
      float4 x1 = *(const float4*)(src + 4);
      bf16x8 v;
      v[0] = f2bf(x0.x); v[1] = f2bf(x0.y); v[2] = f2bf(x0.z); v[3] = f2bf(x0.w);
      v[4] = f2bf(x1.x); v[5] = f2bf(x1.y); v[6] = f2bf(x1.z); v[7] = f2bf(x1.w);
      *(bf16x8*)&As[arow][acol] = v;
      const bf16* bsrc = Wt + (size_t)(c0 + arow) * C_ + k0 + acol;
      *(bf16x8*)&Bs[arow][acol] = *(const bf16x8*)bsrc;
    }
    __syncthreads();
    bf16x8 af[2], bfv[2];
#pragma unroll
    for (int i = 0; i < 2; ++i) af[i] = *(const bf16x8*)&As[wr + i * 16 + li][g * 8];
#pragma unroll
    for (int j = 0; j < 2; ++j) bfv[j] = *(const bf16x8*)&Bs[wc + j * 16 + li][g * 8];
#pragma unroll
    for (int i = 0; i < 2; ++i)
#pragma unroll
      for (int j = 0; j < 2; ++j)
        acc[i][j] = __builtin_amdgcn_mfma_f32_16x16x32_bf16(af[i], bfv[j], acc[i][j], 0, 0, 0);
  }
#pragma unroll
  for (int i = 0; i < 2; ++i)
#pragma unroll
    for (int j = 0; j < 2; ++j) {
      int col = c0 + wc + j * 16 + li;
      float bv = bias[col];
#pragma unroll
      for (int q = 0; q < 4; ++q) {
        int row = r0 + wr + i * 16 + g * 4 + q;
        Out[(size_t)row * C_ + col] = f2bf(acc[i][j][q] + bv);
      }
    }
}

// ---------------- attention: scores->mask->softmax->write attn --------------
// block = (b, 16 q-rows); 8 waves, wave w owns m in [w*256, w*256+256)
__global__ __launch_bounds__(512) void attn_kernel(
    const bf16* __restrict__ Qp, const bf16* __restrict__ Kp,
    const float* __restrict__ key_w, const int* __restrict__ key_m,
    const float* __restrict__ att_f, const int* __restrict__ att_m,
    float* __restrict__ out_attn) {
  int b = blockIdx.y;
  int n0 = blockIdx.x * 16;
  int t = threadIdx.x;
  int w = t >> 6, lane = t & 63, g = lane >> 4, li = lane & 15;
  int m_base = w * 256;

  // factor * key_weight * 1/sqrt(DH), plus combined mask bits, per (tile,q)
  float fe[64];
  unsigned long long mbits = 0ull;
#pragma unroll
  for (int tile = 0; tile < 16; ++tile) {
    int m = m_base + tile * 16 + li;
    float kw = key_w[b * M_ + m];
    int km = key_m[b * M_ + m];
#pragma unroll
    for (int q = 0; q < 4; ++q) {
      int n = n0 + g * 4 + q;
      size_t idx = ((size_t)b * N_ + n) * M_ + m;
      float f = att_f[idx];
      int am = att_m[idx];
      fe[tile * 4 + q] = f * kw * 0.125f;
      if (km | am) mbits |= (1ull << (tile * 4 + q));
    }
  }

  __shared__ float red[2][8][16];

  for (int h = 0; h < H_; ++h) {
    // Q fragment: A[row=n(li)][k], k = g*8+j (+32 for second K-step)
    bf16x8 qf0, qf1;
    {
      const bf16* qbase = Qp + ((size_t)b * N_ + n0 + li) * C_ + h * DH_ + g * 8;
      qf0 = *(const bf16x8*)qbase;
      qf1 = *(const bf16x8*)(qbase + 32);
    }
    f32x4 acc[16];
#pragma unroll
    for (int i = 0; i < 16; ++i)
#pragma unroll
      for (int q = 0; q < 4; ++q) acc[i][q] = 0.0f;

#pragma unroll
    for (int tile = 0; tile < 16; ++tile) {
      const bf16* kbase =
          Kp + ((size_t)b * M_ + m_base + tile * 16 + li) * C_ + h * DH_ + g * 8;
      bf16x8 kf0 = *(const bf16x8*)kbase;
      bf16x8 kf1 = *(const bf16x8*)(kbase + 32);
      acc[tile] = __builtin_amdgcn_mfma_f32_16x16x32_bf16(qf0, kf0, acc[tile], 0, 0, 0);
      acc[tile] = __builtin_amdgcn_mfma_f32_16x16x32_bf16(qf1, kf1, acc[tile], 0, 0, 0);
    }

    // scale + mask + per-lane partial row max (rows live on reg q, group g)
    float pm[4] = {-INFINITY, -INFINITY, -INFINITY, -INFINITY};
#pragma unroll
    for (int tile = 0; tile < 16; ++tile)
#pragma unroll
      for (int q = 0; q < 4; ++q) {
        float s = acc[tile][q] * fe[tile * 4 + q];
        if ((mbits >> (tile * 4 + q)) & 1ull) s = -INFINITY;
        acc[tile][q] = s;
        pm[q] = fmaxf(pm[q], s);
      }
#pragma unroll
    for (int off = 8; off; off >>= 1)
#pragma unroll
      for (int q = 0; q < 4; ++q) pm[q] = fmaxf(pm[q], __shfl_xor(pm[q], off, 64));
    if (li == 0) {
#pragma unroll
      for (int q = 0; q < 4; ++q) red[0][w][g * 4 + q] = pm[q];
    }
    __syncthreads();
    float rm[4];
#pragma unroll
    for (int q = 0; q < 4; ++q) {
      float v = -INFINITY;
#pragma unroll
      for (int ww = 0; ww < 8; ++ww) v = fmaxf(v, red[0][ww][g * 4 + q]);
      rm[q] = v;
    }

    // exp + row sum
    float ps[4] = {0.f, 0.f, 0.f, 0.f};
#pragma unroll
    for (int tile = 0; tile < 16; ++tile)
#pragma unroll
      for (int q = 0; q < 4; ++q) {
        float p = __expf(acc[tile][q] - rm[q]);
        acc[tile][q] = p;
        ps[q] += p;
      }
#pragma unroll
    for (int off = 8; off; off >>= 1)
#pragma unroll
      for (int q = 0; q < 4; ++q) ps[q] += __shfl_xor(ps[q], off, 64);
    if (li == 0) {
#pragma unroll
      for (int q = 0; q < 4; ++q) red[1][w][g * 4 + q] = ps[q];
    }
    __syncthreads();
    float inv[4];
#pragma unroll
    for (int q = 0; q < 4; ++q) {
      float v = 0.f;
#pragma unroll
      for (int ww = 0; ww < 8; ++ww) v += red[1][ww][g * 4 + q];
      inv[q] = 1.0f / v;
    }

    float* abase = out_attn + ((size_t)(b * H_ + h) * N_ + n0) * M_;
#pragma unroll
    for (int tile = 0; tile < 16; ++tile) {
      int m = m_base + tile * 16 + li;
#pragma unroll
      for (int q = 0; q < 4; ++q) {
        abase[(size_t)(g * 4 + q) * M_ + m] = acc[tile][q] * inv[q];
      }
    }
  }
}

// ---------------- PV GEMM: hidden[b][n][h*64+d] = sum_m attn * V -----------
__global__ __launch_bounds__(256) void pv_gemm(const float* __restrict__ attn,
                                               const bf16* __restrict__ Vt,
                                               float* __restrict__ hidden) {
  int bh = blockIdx.y;
  int b = bh >> 3, h = bh & 7;
  int n0 = blockIdx.x * 64;
  __shared__ bf16 As[64][40];
  int t = threadIdx.x;
  int w = t >> 6, lane = t & 63, g = lane >> 4, li = lane & 15;
  int wr = (w >> 1) * 32, wc = (w & 1) * 32;
  int arow = t >> 2, acol = (t & 3) * 8;
  const float* abase = attn + ((size_t)bh * N_ + n0) * M_;
  const bf16* vbase = Vt + ((size_t)b * C_ + h * DH_) * M_;

  f32x4 acc[2][2];
#pragma unroll
  for (int i = 0; i < 2; ++i)
#pragma unroll
    for (int j = 0; j < 2; ++j)
#pragma unroll
      for (int q = 0; q < 4; ++q) acc[i][j][q] = 0.0f;

  for (int k0 = 0; k0 < M_; k0 += 32) {
    __syncthreads();
    {
      const float* src = abase + (size_t)arow * M_ + k0 + acol;
      float4 x0 = *(const float4*)src;
      float4 x1 = *(const float4*)(src + 4);
      bf16x8 v;
      v[0] = f2bf(x0.x); v[1] = f2bf(x0.y); v[2] = f2bf(x0.z); v[3] = f2bf(x0.w);
      v[4] = f2bf(x1.x); v[5] = f2bf(x1.y); v[6] = f2bf(x1.z); v[7] = f2bf(x1.w);
      *(bf16x8*)&As[arow][acol] = v;
    }
    __syncthreads();
    bf16x8 af[2], bfv[2];
#pragma unroll
    for (int i = 0; i < 2; ++i) af[i] = *(const bf16x8*)&As[wr + i * 16 + li][g * 8];
#pragma unroll
    for (int j = 0; j < 2; ++j) {
      const bf16* vsrc = vbase + (size_t)(wc + j * 16 + li) * M_ + k0 + g * 8;
      bfv[j] = *(const bf16x8*)vsrc;
    }
#pragma unroll
    for (int i = 0; i < 2; ++i)
#pragma unroll
      for (int j = 0; j < 2; ++j)
        acc[i][j] = __builtin_amdgcn_mfma_f32_16x16x32_bf16(af[i], bfv[j], acc[i][j], 0, 0, 0);
  }
#pragma unroll
  for (int i = 0; i < 2; ++i)
#pragma unroll
    for (int j = 0; j < 2; ++j) {
      int d = wc + j * 16 + li;
#pragma unroll
      for (int q = 0; q < 4; ++q) {
        int n = n0 + wr + i * 16 + g * 4 + q;
        hidden[((size_t)(b * N_ + n)) * C_ + h * DH_ + d] = acc[i][j][q];
      }
    }
}

extern "C" void kernel_launch(void* const* d_in, const int* in_sizes, int n_in,
                              void* d_out, int out_size, void* d_ws, size_t ws_size,
                              hipStream_t stream) {
  const float* input_q = (const float*)d_in[0];
  const float* input_k = (const float*)d_in[1];
  const float* input_v = (const float*)d_in[2];
  const float* key_w   = (const float*)d_in[3];
  const int*   key_m   = (const int*)d_in[4];
  const float* att_f   = (const float*)d_in[5];
  const int*   att_m   = (const int*)d_in[6];
  const float* Wq      = (const float*)d_in[7];
  const float* bq      = (const float*)d_in[8];
  const float* Wk      = (const float*)d_in[9];
  const float* bk      = (const float*)d_in[10];
  const float* Wv      = (const float*)d_in[11];
  const float* bv      = (const float*)d_in[12];

  const size_t PROJ_ELEMS = (size_t)B_ * N_ * C_;  // 4,194,304
  bf16* Qp = (bf16*)d_ws;
  bf16* Kp = Qp + PROJ_ELEMS;
  bf16* Vp = Kp + PROJ_ELEMS;
  bf16* Vt = Vp + PROJ_ELEMS;
  bf16* Wt = Vt + PROJ_ELEMS;  // 3 x 512x512 bf16

  float* out    = (float*)d_out;
  float* hidden = out;                       // (B,N,C)
  float* attn   = out + PROJ_ELEMS;          // (B,H,N,M)

  dim3 tb(32, 32);
  transpose_w<<<dim3(16, 16), tb, 0, stream>>>(Wq, Wt);
  transpose_w<<<dim3(16, 16), tb, 0, stream>>>(Wk, Wt + 512 * 512);
  transpose_w<<<dim3(16, 16), tb, 0, stream>>>(Wv, Wt + 2 * 512 * 512);

  proj_gemm<<<dim3(8, 128), 256, 0, stream>>>(input_q, Wt, bq, Qp);
  proj_gemm<<<dim3(8, 128), 256, 0, stream>>>(input_k, Wt + 512 * 512, bk, Kp);
  proj_gemm<<<dim3(8, 128), 256, 0, stream>>>(input_v, Wt + 2 * 512 * 512, bv, Vp);

  transpose_v<<<dim3(64, 16, 4), tb, 0, stream>>>(Vp, Vt);

  attn_kernel<<<dim3(128, 4), 512, 0, stream>>>(Qp, Kp, key_w, key_m, att_f, att_m, attn);

  pv_gemm<<<dim3(32, 32), 256, 0, stream>>>(attn, Vt, hidden);
}